// Round 7
// baseline (193.528 us; speedup 1.0000x reference)
//
#include <hip/hip_runtime.h>
#include <stdint.h>

typedef unsigned int u32;
typedef unsigned long long u64;

#define N_ITEMS 131072
#define NB 131072                   // buckets (monotone in descending score)
#define NSLICE 8                    // XCD-sliced histogram copies
#define CHUNK 64
#define NCHUNKS 2048                // NB / CHUNK
#define SCAN_BLOCKS 512             // NB / 256
#define FIXSCALE 268435456.0f       // 2^28 fixed-point scale for sum(exp)
#define FIXMASK ((1ull << 46) - 1)

// ---------- helpers ----------

// sum_{i=s}^{e} (N - i) — exact weight-side sum of exp(w) over sorted positions
__device__ __forceinline__ float wsumf(int s, int e) {
  return 0.5f * (float)(e - s + 1) * (float)(2 * N_ITEMS - s - e);
}

__device__ __forceinline__ float key_to_score(u32 key) {
  u32 m = ~key;
  u32 u = (m & 0x80000000u) ? (m ^ 0x80000000u) : ~m;
  return __uint_as_float(u);
}

#define LOG2E 1.4426950408889634f
__device__ __forceinline__ float fexp(float x) { return exp2f(x * LOG2E); }

// ascending key == descending score; ascending bucket == descending score
__device__ __forceinline__ u32 bucket_of(u32 key, u32 kmin, u32 kmax) {
  double scale = (double)NB / ((double)(kmax - kmin) + 1.0);
  u32 b = (u32)((double)(key - kmin) * scale);
  return b < NB ? b : (NB - 1);
}

// ---------- deque primitives: records live in slots [c*64, c*64+64) ----------
// be[c] packs beg (hi16) / end (lo16).

__device__ __forceinline__ bool peek_next(const u32* be, int c1, int c, int k,
                                          int& nc, int& nk) {
  u32 w = be[c];
  if (k + 1 < (int)(w & 0xFFFFu)) { nc = c; nk = k + 1; return true; }
  for (int cc = c + 1; cc < c1; ++cc) {
    w = be[cc];
    if ((int)(w >> 16) < (int)(w & 0xFFFFu)) { nc = cc; nk = (int)(w >> 16); return true; }
  }
  return false;
}

__device__ __forceinline__ bool pop_tail(u32* be, int c0, int& tc, int& tk) {
  be[tc] = (be[tc] & 0xFFFF0000u) | (u32)tk;      // end = tk (record removed)
  if ((int)(be[tc] >> 16) < tk) { --tk; return true; }
  for (int c = tc - 1; c >= c0; --c) {
    u32 w = be[c];
    if ((int)(w >> 16) < (int)(w & 0xFFFFu)) { tc = c; tk = (int)(w & 0xFFFFu) - 1; return true; }
  }
  return false;
}

__device__ __forceinline__ bool pop_head(u32* be, int c1, int& hc, int& hk) {
  be[hc] = (be[hc] & 0x0000FFFFu) | ((u32)(hk + 1) << 16); // beg = hk+1
  u32 w = be[hc];
  if ((int)(w >> 16) < (int)(w & 0xFFFFu)) { ++hk; return true; }
  for (int c = hc + 1; c < c1; ++c) {
    w = be[c];
    if ((int)(w >> 16) < (int)(w & 0xFFFFu)) { hc = c; hk = (int)(w >> 16); return true; }
  }
  return false;
}

// ---------- 1) scores -> keys, per-block minmax partials, all buffer zeroing ----------

__global__ void score_key_kernel(const float* __restrict__ x,
                                 const float* __restrict__ w1,
                                 const float* __restrict__ b1,
                                 const float* __restrict__ w2,
                                 const float* __restrict__ b2,
                                 u32* __restrict__ keyRaw,
                                 u32* __restrict__ pmin, u32* __restrict__ pmax,
                                 u64* __restrict__ hist8, u64* __restrict__ flags) {
  __shared__ u32 r0[256], r1[256];
  int t = threadIdx.x;
  int i = blockIdx.x * 256 + t;
#pragma unroll
  for (int k = 0; k < NSLICE; ++k) hist8[(size_t)k * NB + i] = 0ull;
  if (i < SCAN_BLOCKS) flags[i] = 0ull;
  float xv = x[i];
  float s = b2[0];
#pragma unroll
  for (int j = 0; j < 32; ++j) {
    float h = fmaf(xv, w1[j], b1[j]);
    h = fmaxf(h, 0.0f);
    s = fmaf(h, w2[j], s);
  }
  u32 u = __float_as_uint(s);
  u32 m = u ^ ((u & 0x80000000u) ? 0xFFFFFFFFu : 0x80000000u); // ascending map
  u32 key = ~m;
  keyRaw[i] = key;
  r0[t] = key; r1[t] = key;
  __syncthreads();
  for (int off = 128; off > 0; off >>= 1) {
    if (t < off) { r0[t] = min(r0[t], r0[t + off]); r1[t] = max(r1[t], r1[t + off]); }
    __syncthreads();
  }
  if (t == 0) { pmin[blockIdx.x] = r0[0]; pmax[blockIdx.x] = r1[0]; }
}

// ---------- 2) bucket aggregates: ONE packed u64 atomic per item, XCD-sliced ----------

__global__ void hist_kernel(const u32* __restrict__ keyRaw,
                            const u32* __restrict__ pmin, const u32* __restrict__ pmax,
                            u64* __restrict__ hist8, u32* __restrict__ mm) {
  __shared__ u32 s0[256], s1[256];
  int t = threadIdx.x;
  s0[t] = min(pmin[t], pmin[t + 256]);
  s1[t] = max(pmax[t], pmax[t + 256]);
  __syncthreads();
  for (int off = 128; off > 0; off >>= 1) {
    if (t < off) { s0[t] = min(s0[t], s0[t + off]); s1[t] = max(s1[t], s1[t + off]); }
    __syncthreads();
  }
  u32 kmin = s0[0], kmax = s1[0];
  if (blockIdx.x == 0 && t == 0) { mm[0] = kmin; mm[1] = kmax; }
  int i = blockIdx.x * 256 + t;
  u32 key = keyRaw[i];
  u32 g = bucket_of(key, kmin, kmax);
  float smax = key_to_score(kmin);
  float v = fexp(key_to_score(key) - smax);            // in (0, 1]
  u64 fix = (u64)fmaxf(1.0f, fmaf(v, FIXSCALE, 0.5f)); // clamp: SY can never be 0
  size_t slice = (size_t)(blockIdx.x & (NSLICE - 1)) * NB;
  atomicAdd(&hist8[slice + g], (1ull << 46) | fix);
}

// ---------- 3) fused: 8-way reduce + lookback scan + per-chunk PAV from LDS ----------

__global__ __launch_bounds__(256) void scan_pav_kernel(const u64* __restrict__ hist8,
                                                       u64* __restrict__ flags,
                                                       u32* __restrict__ cdf,
                                                       u32* __restrict__ cstart,
                                                       float* __restrict__ SY,
                                                       int* __restrict__ ST,
                                                       u32* __restrict__ be,
                                                       int* __restrict__ hC,
                                                       int* __restrict__ tC) {
  __shared__ u32 sh[256];
  __shared__ float seL[256];
  __shared__ u32 cdfL[257];
  __shared__ u32 exclu_s;
  __shared__ u32 stkST[64][4];
  __shared__ float stkSY[64][4];
  int t = threadIdx.x, b = blockIdx.x;
  int i = b * 256 + t;
  u64 acc = 0;
#pragma unroll
  for (int c = 0; c < NSLICE; ++c) acc += hist8[(size_t)c * NB + i];
  u32 v = (u32)(acc >> 46);
  seL[t] = (float)(acc & FIXMASK) * (1.0f / FIXSCALE);
  sh[t] = v;
  __syncthreads();
  for (int off = 1; off < 256; off <<= 1) {
    u32 x2 = (t >= off) ? sh[t - off] : 0u;
    __syncthreads();
    sh[t] += x2;
    __syncthreads();
  }
  if (t == 0) {
    u32 agg = sh[255];
    if (b == 0) {
      atomicExch(&flags[0], (2ull << 32) | (u64)agg);
      exclu_s = 0u;
    } else {
      atomicExch(&flags[b], (1ull << 32) | (u64)agg);
      u32 ex = 0; int j = b - 1;
      for (;;) {
        u64 f = atomicAdd(&flags[j], 0ull);     // device-scope load
        u32 st = (u32)(f >> 32);
        if (st == 0u) continue;                 // spin: 512 blocks all co-resident
        ex += (u32)f;
        if (st == 2u) break;
        --j;
      }
      atomicExch(&flags[b], (2ull << 32) | (u64)(ex + agg));
      exclu_s = ex;
    }
  }
  __syncthreads();
  u32 exclu = exclu_s;
  u32 e = sh[t] - v + exclu;                    // exclusive global prefix = cdf
  cdfL[t] = e;
  if (t == 255) cdfL[256] = exclu + sh[255];
  cdf[i] = e;
  if ((t & 63) == 0) cstart[i >> 6] = e;
  if (i == 0) cstart[NCHUNKS] = N_ITEMS;
  __syncthreads();
  // PAV for this block's 4 chunks, entirely from LDS
  if (t < 4) {
    int c = b * 4 + t;
    int ptr = 0; bool have = false;
    float syT = 0.0f; int stT = 0;
    for (int k = 0; k < 64; ++k) {
      u32 cs = cdfL[t * 64 + k], ce = cdfL[t * 64 + k + 1];
      if (ce == cs) continue;
      float syC = seL[t * 64 + k];
      int stC = (int)cs, eC = (int)ce - 1;
      while (have) {
        float SWc = wsumf(stC, eC);
        float SWt = wsumf(stT, stC - 1);
        if (!(syT * SWc <= syC * SWt)) break;
        syC += syT; stC = stT;
        if (ptr == 0) { have = false; break; }
        --ptr;
        stT = (int)stkST[ptr][t]; syT = stkSY[ptr][t];
      }
      if (have) { stkST[ptr][t] = (u32)stT; stkSY[ptr][t] = syT; ++ptr; }
      stT = stC; syT = syC; have = true;
    }
    int slotBase = c * 64;
    for (int k2 = 0; k2 < ptr; ++k2) {
      ST[slotBase + k2] = (int)stkST[k2][t];
      SY[slotBase + k2] = stkSY[k2][t];
    }
    int n = ptr;
    if (have) { ST[slotBase + n] = stT; SY[slotBase + n] = syT; ++n; }
    be[c] = (u32)n;                 // beg=0, end=n
    hC[c] = tC[c] = (n > 0) ? c : -1;
  }
}

// ---------- 4) deque pair-merge: pops + one push, NO compaction ----------

__device__ void merge_pair(int c0, int cm, int c1,
                           float* __restrict__ SY, int* __restrict__ ST,
                           u32* __restrict__ be, int* __restrict__ hC, int* __restrict__ tC,
                           const u32* __restrict__ cstart) {
  int hR = hC[cm];
  if (hR < 0) return;                              // R empty
  int hL = hC[c0];
  if (hL < 0) { hC[c0] = hR; tC[c0] = tC[cm]; return; }
  int tL = tC[c0], tR = tC[cm];
  // L tail record
  int ltc = tL, ltk = (int)(be[tL] & 0xFFFFu) - 1;
  float SYL = SY[ltc * 64 + ltk]; int stL = ST[ltc * 64 + ltk];
  int eL = (int)cstart[cm] - 1;
  // R head record
  int rhc = hR, rhk = (int)(be[hR] >> 16);
  float SYR = SY[rhc * 64 + rhk]; int stR = ST[rhc * 64 + rhk];
  int nc, nk;
  int eR = peek_next(be, c1, rhc, rhk, nc, nk) ? ST[nc * 64 + nk] - 1
                                               : (int)cstart[c1] - 1;
  float SWL = wsumf(stL, eL);
  float SWR = wsumf(stR, eR);
  if (!(SYL * SWR <= SYR * SWL)) { tC[c0] = tR; return; }   // no violation; union tail
  // pool boundary records into M, cascade
  float SYM = SYL + SYR; int Ms = stL, Me = eR;
  int lastPc = ltc;
  bool Lne = pop_tail(be, c0, ltc, ltk);
  bool Rne = pop_head(be, c1, rhc, rhk);
  for (;;) {
    float SWM = wsumf(Ms, Me);
    if (Lne) {
      float SYe = SY[ltc * 64 + ltk]; int ste = ST[ltc * 64 + ltk];
      float SWe = wsumf(ste, Ms - 1);
      if (SYe * SWM <= SYM * SWe) {
        SYM += SYe; Ms = ste;
        lastPc = ltc;
        Lne = pop_tail(be, c0, ltc, ltk);
        continue;
      }
    }
    if (Rne) {
      float SYb = SY[rhc * 64 + rhk]; int sb = ST[rhc * 64 + rhk];
      int eb = peek_next(be, c1, rhc, rhk, nc, nk) ? ST[nc * 64 + nk] - 1
                                                   : (int)cstart[c1] - 1;
      float SWb = wsumf(sb, eb);
      if (SYM * SWb <= SYb * SWM) {
        SYM += SYb; Me = eb;
        Rne = pop_head(be, c1, rhc, rhk);
        continue;
      }
    }
    break;
  }
  // push M at the deepest-popped L chunk's tail (slot guaranteed free)
  u32 w = be[lastPc];
  int ee = (int)(w & 0xFFFFu);
  ST[lastPc * 64 + ee] = Ms; SY[lastPc * 64 + ee] = SYM;
  be[lastPc] = (w & 0xFFFF0000u) | (u32)(ee + 1);
  u32 hb = be[hL];
  hC[c0] = ((int)(hb >> 16) < (int)(hb & 0xFFFFu)) ? hL : lastPc;
  tC[c0] = Rne ? tR : lastPc;
}

__global__ void merge_deque_kernel(float* __restrict__ SY, int* __restrict__ ST,
                                   u32* __restrict__ be, int* __restrict__ hC,
                                   int* __restrict__ tC, const u32* __restrict__ cstart,
                                   u32* __restrict__ pref,
                                   int l0, int L, int do_pref) {
  int t = threadIdx.x;
  int G = 1 << L;                  // incoming groups per block
  int SC = 1 << l0;                // chunks per incoming group
  int baseC = blockIdx.x * G * SC;
  for (int j = 0; j < L; ++j) {
    int P = G >> (j + 1);
    if (t < P) {
      int GC = SC << j;
      int c0 = baseC + (t << (j + 1)) * SC;
      merge_pair(c0, c0 + GC, c0 + 2 * GC, SY, ST, be, hC, tC, cstart);
    }
    __syncthreads();
  }
  if (do_pref) {
    // exclusive prefix over 2048 chunk record-counts (256 threads x 8)
    __shared__ u32 psum[256];
    u32 loc[8]; u32 s = 0;
    for (int q = 0; q < 8; ++q) {
      u32 w = be[t * 8 + q];
      loc[q] = s; s += (w & 0xFFFFu) - (w >> 16);
    }
    psum[t] = s;
    __syncthreads();
    for (int off = 1; off < 256; off <<= 1) {
      u32 x2 = (t >= off) ? psum[t - off] : 0u;
      __syncthreads();
      psum[t] += x2;
      __syncthreads();
    }
    u32 base = (t == 0) ? 0u : psum[t - 1];
    for (int q = 0; q < 8; ++q) pref[t * 8 + q] = base + loc[q];
    if (t == 255) pref[NCHUNKS] = psum[255];
  }
}

// ---------- 5) parallel compaction gather ----------

__global__ void gather_kernel(const float* __restrict__ SY, const int* __restrict__ ST,
                              const u32* __restrict__ be, const u32* __restrict__ pref,
                              float* __restrict__ SYc, int* __restrict__ STc) {
  int i = blockIdx.x * 256 + threadIdx.x;    // slot
  int c = i >> 6, k = i & 63;
  u32 w = be[c];
  int b = (int)(w >> 16), e = (int)(w & 0xFFFFu);
  if (k >= b && k < e) {
    int dst = (int)pref[c] + (k - b);
    STc[dst] = ST[i]; SYc[dst] = SY[i];
  }
}

// ---------- 6) ranks + transform, fully coalesced output ----------

__global__ void out_kernel(const u32* __restrict__ keyRaw, const u32* __restrict__ mm,
                           const u32* __restrict__ cdf, const u32* __restrict__ pref,
                           const float* __restrict__ SYc, const int* __restrict__ STc,
                           float* __restrict__ out) {
  int i = blockIdx.x * 256 + threadIdx.x;
  u32 key = keyRaw[i];
  u32 kmin = mm[0], kmax = mm[1];
  float smax = key_to_score(kmin);
  u32 g = bucket_of(key, kmin, kmax);
  int p = (int)cdf[g];               // block is bucket-aligned: position of bucket start
  int m = (int)pref[NCHUNKS];
  int lo = 0, hi = m - 1;
  while (lo < hi) {
    int mid = (lo + hi + 1) >> 1;
    if (STc[mid] <= p) lo = mid; else hi = mid - 1;
  }
  int s0 = STc[lo];
  int e0 = (lo + 1 < m) ? (STc[lo + 1] - 1) : (N_ITEMS - 1);
  float SW = wsumf(s0, e0);
  float s = key_to_score(key);
  float rank = fexp(s - smax) * SW / SYc[lo];
  out[i] = floorf(rank * (1.0f / 3.0f)) + 1.0f;
}

// ---------- launch ----------

extern "C" void kernel_launch(void* const* d_in, const int* in_sizes, int n_in,
                              void* d_out, int out_size, void* d_ws, size_t ws_size,
                              hipStream_t stream) {
  const float* x  = (const float*)d_in[0];
  const float* w1 = (const float*)d_in[1];
  const float* b1 = (const float*)d_in[2];
  const float* w2 = (const float*)d_in[3];
  const float* b2 = (const float*)d_in[4];
  float* out = (float*)d_out;

  char* ws = (char*)d_ws;
  size_t o = 0;
  u32* mm     = (u32*)(ws + o); o += 16;
  u32* pmin   = (u32*)(ws + o); o += (size_t)SCAN_BLOCKS * 4;
  u32* pmax   = (u32*)(ws + o); o += (size_t)SCAN_BLOCKS * 4;
  u64* hist8  = (u64*)(ws + o); o += (size_t)NSLICE * NB * 8;    // 8 MB, XCD-sliced
  u64* flags  = (u64*)(ws + o); o += (size_t)SCAN_BLOCKS * 8;
  u32* cdf    = (u32*)(ws + o); o += (size_t)(NB + 4) * 4;
  u32* cstart = (u32*)(ws + o); o += (size_t)(NCHUNKS + 4) * 4;
  u32* pref   = (u32*)(ws + o); o += (size_t)(NCHUNKS + 4) * 4;
  u32* keyRaw = (u32*)(ws + o); o += (size_t)N_ITEMS * 4;
  float* SY   = (float*)(ws + o); o += (size_t)N_ITEMS * 4;
  int* ST     = (int*)(ws + o);   o += (size_t)N_ITEMS * 4;
  float* SYc  = (float*)(ws + o); o += (size_t)N_ITEMS * 4;
  int* STc    = (int*)(ws + o);   o += (size_t)N_ITEMS * 4;
  u32* be     = (u32*)(ws + o);   o += (size_t)NCHUNKS * 4;
  int* hC     = (int*)(ws + o);   o += (size_t)NCHUNKS * 4;
  int* tC     = (int*)(ws + o);   o += (size_t)NCHUNKS * 4;

  score_key_kernel<<<SCAN_BLOCKS, 256, 0, stream>>>(x, w1, b1, w2, b2,
                                                    keyRaw, pmin, pmax, hist8, flags);
  hist_kernel<<<SCAN_BLOCKS, 256, 0, stream>>>(keyRaw, pmin, pmax, hist8, mm);
  scan_pav_kernel<<<SCAN_BLOCKS, 256, 0, stream>>>(hist8, flags, cdf, cstart,
                                                   SY, ST, be, hC, tC);
  // 11 tree levels in 2 launches: 0-4 (64 blocks x 64 thr), 5-10 (+prefix, 1 block x 256)
  merge_deque_kernel<<<64, 64, 0, stream>>>(SY, ST, be, hC, tC, cstart, pref, 0, 5, 0);
  merge_deque_kernel<<<1, 256, 0, stream>>>(SY, ST, be, hC, tC, cstart, pref, 5, 6, 1);
  gather_kernel<<<SCAN_BLOCKS, 256, 0, stream>>>(SY, ST, be, pref, SYc, STc);
  out_kernel<<<SCAN_BLOCKS, 256, 0, stream>>>(keyRaw, mm, cdf, pref, SYc, STc, out);
}

// Round 8
// 133.249 us; speedup vs baseline: 1.4524x; 1.4524x over previous
//
#include <hip/hip_runtime.h>
#include <stdint.h>

typedef unsigned int u32;
typedef unsigned long long u64;

#define N_ITEMS 131072
#define NB 131072                   // buckets (monotone in descending score)
#define NSLICE 4                    // XCD-sliced histogram copies
#define CHUNK 64
#define NCHUNKS 2048                // NB / CHUNK
#define SCAN_BLOCKS 512             // NB / 256
#define FIXSCALE 268435456.0f       // 2^28 fixed-point scale for sum(exp)
#define FIXMASK ((1ull << 46) - 1)

// ---------- helpers ----------

// sum_{i=s}^{e} (N - i) — exact weight-side sum of exp(w) over sorted positions
__device__ __forceinline__ float wsumf(int s, int e) {
  return 0.5f * (float)(e - s + 1) * (float)(2 * N_ITEMS - s - e);
}

__device__ __forceinline__ float key_to_score(u32 key) {
  u32 m = ~key;
  u32 u = (m & 0x80000000u) ? (m ^ 0x80000000u) : ~m;
  return __uint_as_float(u);
}

#define LOG2E 1.4426950408889634f
__device__ __forceinline__ float fexp(float x) { return exp2f(x * LOG2E); }

// ascending key == descending score; ascending bucket == descending score
__device__ __forceinline__ u32 bucket_of(u32 key, u32 kmin, u32 kmax) {
  double scale = (double)NB / ((double)(kmax - kmin) + 1.0);
  u32 b = (u32)((double)(key - kmin) * scale);
  return b < NB ? b : (NB - 1);
}

// record = int2 { x = ST (start position), y = SY bits (float) }
__device__ __forceinline__ float recSY(int2 r) { return __int_as_float(r.y); }

// ---------- 1) scores -> keys, per-block minmax partials, all buffer zeroing ----------

__global__ void score_key_kernel(const float* __restrict__ x,
                                 const float* __restrict__ w1,
                                 const float* __restrict__ b1,
                                 const float* __restrict__ w2,
                                 const float* __restrict__ b2,
                                 u32* __restrict__ keyRaw,
                                 u32* __restrict__ pmin, u32* __restrict__ pmax,
                                 u64* __restrict__ hist8, u64* __restrict__ flags) {
  __shared__ u32 r0[256], r1[256];
  int t = threadIdx.x;
  int i = blockIdx.x * 256 + t;
  // cooperative zero of the sliced histogram (fully coalesced per slice)
#pragma unroll
  for (int k = 0; k < NSLICE; ++k) hist8[(size_t)k * NB + i] = 0ull;
  if (i < SCAN_BLOCKS) flags[i] = 0ull;
  float xv = x[i];
  float s = b2[0];
#pragma unroll
  for (int j = 0; j < 32; ++j) {
    float h = fmaf(xv, w1[j], b1[j]);
    h = fmaxf(h, 0.0f);
    s = fmaf(h, w2[j], s);
  }
  u32 u = __float_as_uint(s);
  u32 m = u ^ ((u & 0x80000000u) ? 0xFFFFFFFFu : 0x80000000u); // ascending map
  u32 key = ~m;
  keyRaw[i] = key;
  r0[t] = key; r1[t] = key;
  __syncthreads();
  for (int off = 128; off > 0; off >>= 1) {
    if (t < off) { r0[t] = min(r0[t], r0[t + off]); r1[t] = max(r1[t], r1[t + off]); }
    __syncthreads();
  }
  if (t == 0) { pmin[blockIdx.x] = r0[0]; pmax[blockIdx.x] = r1[0]; }
}

// ---------- 2) bucket aggregates: ONE packed u64 atomic per item, XCD-sliced ----------
// bits [46:63] = count, bits [0:45] = fixed-point (2^28) sum of exp(s - smax)

__global__ void hist_kernel(const u32* __restrict__ keyRaw,
                            const u32* __restrict__ pmin, const u32* __restrict__ pmax,
                            u64* __restrict__ hist8, u32* __restrict__ mm) {
  __shared__ u32 s0[256], s1[256];
  int t = threadIdx.x;
  s0[t] = min(pmin[t], pmin[t + 256]);
  s1[t] = max(pmax[t], pmax[t + 256]);
  __syncthreads();
  for (int off = 128; off > 0; off >>= 1) {
    if (t < off) { s0[t] = min(s0[t], s0[t + off]); s1[t] = max(s1[t], s1[t + off]); }
    __syncthreads();
  }
  u32 kmin = s0[0], kmax = s1[0];
  if (blockIdx.x == 0 && t == 0) { mm[0] = kmin; mm[1] = kmax; }  // for out_kernel
  int i = blockIdx.x * 256 + t;
  u32 key = keyRaw[i];
  u32 g = bucket_of(key, kmin, kmax);
  float smax = key_to_score(kmin);
  float v = fexp(key_to_score(key) - smax);            // in (0, 1]
  u64 fix = (u64)fmaxf(1.0f, fmaf(v, FIXSCALE, 0.5f)); // clamp: SY can never be 0
  size_t slice = (size_t)(blockIdx.x & (NSLICE - 1)) * NB;
  atomicAdd(&hist8[slice + g], (1ull << 46) | fix);
}

// ---------- 3) fused: reduce + lookback scan + per-chunk PAV from LDS ----------
// A scan block owns 256 buckets = 4 chunks; its inclusive aggregate is the chunk-end
// boundary, so PAV for those chunks needs nothing beyond block-local data.

__global__ __launch_bounds__(256) void scan_pav_kernel(const u64* __restrict__ hist8,
                                                       u64* __restrict__ flags,
                                                       u32* __restrict__ cdf,
                                                       u32* __restrict__ cstart,
                                                       int2* __restrict__ REC,
                                                       int* __restrict__ cnt) {
  __shared__ u32 sh[256];
  __shared__ float seL[256];
  __shared__ u32 cdfL[257];
  __shared__ u32 exclu_s;
  __shared__ u32 stkST[64][4];
  __shared__ float stkSY[64][4];
  int t = threadIdx.x, b = blockIdx.x;
  int i = b * 256 + t;
  u64 acc = 0;
#pragma unroll
  for (int c = 0; c < NSLICE; ++c) acc += hist8[(size_t)c * NB + i];
  u32 v = (u32)(acc >> 46);
  seL[t] = (float)(acc & FIXMASK) * (1.0f / FIXSCALE);
  sh[t] = v;
  __syncthreads();
  for (int off = 1; off < 256; off <<= 1) {
    u32 x2 = (t >= off) ? sh[t - off] : 0u;
    __syncthreads();
    sh[t] += x2;
    __syncthreads();
  }
  if (t == 0) {
    u32 agg = sh[255];
    if (b == 0) {
      atomicExch(&flags[0], (2ull << 32) | (u64)agg);
      exclu_s = 0u;
    } else {
      atomicExch(&flags[b], (1ull << 32) | (u64)agg);
      u32 ex = 0; int j = b - 1;
      for (;;) {
        u64 f = atomicAdd(&flags[j], 0ull);     // device-scope load
        u32 st = (u32)(f >> 32);
        if (st == 0u) continue;                 // spin: 512 blocks all co-resident
        ex += (u32)f;
        if (st == 2u) break;
        --j;
      }
      atomicExch(&flags[b], (2ull << 32) | (u64)(ex + agg));
      exclu_s = ex;
    }
  }
  __syncthreads();
  u32 exclu = exclu_s;
  u32 e = sh[t] - v + exclu;                    // exclusive global prefix = cdf
  cdfL[t] = e;
  if (t == 255) cdfL[256] = exclu + sh[255];    // block-end boundary
  cdf[i] = e;
  if ((t & 63) == 0) cstart[i >> 6] = e;        // chunk element starts
  if (i == 0) cstart[NCHUNKS] = N_ITEMS;
  __syncthreads();
  // PAV for this block's 4 chunks, entirely from LDS
  if (t < 4) {
    int c = b * 4 + t;
    int ptr = 0; bool have = false;
    float syT = 0.0f; int stT = 0;
    for (int k = 0; k < 64; ++k) {
      u32 cs = cdfL[t * 64 + k], ce = cdfL[t * 64 + k + 1];
      if (ce == cs) continue;                 // empty bucket
      float syC = seL[t * 64 + k];
      int stC = (int)cs, eC = (int)ce - 1;
      while (have) {
        float SWc = wsumf(stC, eC);
        float SWt = wsumf(stT, stC - 1);
        if (!(syT * SWc <= syC * SWt)) break; // merge while val_top <= val_cur
        syC += syT; stC = stT;
        if (ptr == 0) { have = false; break; }
        --ptr;
        stT = (int)stkST[ptr][t]; syT = stkSY[ptr][t];
      }
      if (have) { stkST[ptr][t] = (u32)stT; stkSY[ptr][t] = syT; ++ptr; }
      stT = stC; syT = syC; have = true;
    }
    int slotBase = c * 64;
    for (int k2 = 0; k2 < ptr; ++k2)
      REC[slotBase + k2] = make_int2((int)stkST[k2][t], __float_as_int(stkSY[k2][t]));
    int n = ptr;
    if (have) { REC[slotBase + n] = make_int2(stT, __float_as_int(syT)); ++n; }
    cnt[c] = n;
  }
}

// ---------- 4) multi-level tree merge (array records + staged compaction) ----------

__global__ void merge_multi_kernel(int2* __restrict__ REC,
                                   int* __restrict__ cnt, const u32* __restrict__ cstart,
                                   int l0, int L) {
  __shared__ int lcnt[64];
  __shared__ int ca[32], cb[32], cM[32];
  int t = threadIdx.x;
  int G = 1 << L;                  // incoming groups per block
  int SC = 1 << l0;                // chunks per incoming group
  int baseC = blockIdx.x * G * SC;
  if (t < G) lcnt[t] = cnt[baseC + t * SC];
  __syncthreads();
  for (int j = 0; j < L; ++j) {
    int P = G >> (j + 1);
    if (t < P) {
      int p = t;
      int kL = p << (j + 1), kR = kL + (1 << j);
      int slotL = (baseC + kL * SC) * 64, slotR = (baseC + kR * SC) * 64;
      int nL = lcnt[kL], nR = lcnt[kR];
      int a = 0, b = 0, hasM = 0;
      if (nL > 0 && nR > 0) {
        int gstartR = (int)cstart[baseC + kR * SC];
        int gendR   = (int)cstart[baseC + (kR + (1 << j)) * SC];
        int2 rL = REC[slotL + nL - 1];
        float SYL = recSY(rL); int stL = rL.x;
        int2 rR = REC[slotR];
        float SYR = recSY(rR);
        int eR = (nR > 1) ? (REC[slotR + 1].x - 1) : (gendR - 1);
        float SWL = wsumf(stL, gstartR - 1);
        float SWR = wsumf(gstartR, eR);
        if (SYL * SWR <= SYR * SWL) {
          hasM = 1;
          float SYM = SYL + SYR; int Ms = stL, Me = eR;
          a = 1; b = 1;
          for (;;) {
            float SWM = wsumf(Ms, Me);
            if (a < nL) {
              int2 re = REC[slotL + nL - 1 - a];
              float SYe = recSY(re); int ste = re.x;
              float SWe = wsumf(ste, Ms - 1);
              if (SYe * SWM <= SYM * SWe) { SYM += SYe; Ms = ste; ++a; continue; }
            }
            if (b < nR) {
              int2 rb = REC[slotR + b];
              float SYb = recSY(rb); int sb = rb.x;
              int eb = (b + 1 < nR) ? (REC[slotR + b + 1].x - 1) : (gendR - 1);
              float SWb = wsumf(sb, eb);
              if (SYM * SWb <= SYb * SWM) { SYM += SYb; Me = eb; ++b; continue; }
            }
            break;
          }
          REC[slotL + nL - a] = make_int2(Ms, __float_as_int(SYM)); // below copy dest
        }
      }
      ca[p] = a; cb[p] = b; cM[p] = hasM;
    }
    __syncthreads();
    // staged compaction copies (dest <= src)
    for (int p = 0; p < P; ++p) {
      int kL = p << (j + 1), kR = kL + (1 << j);
      int nL = lcnt[kL], nR = lcnt[kR];
      int a = ca[p], b = cb[p], hasM = cM[p];
      int slotL = (baseC + kL * SC) * 64, slotR = (baseC + kR * SC) * 64;
      int destBase = slotL + nL - a + hasM;
      int srcBase = slotR + b;
      int ncopy = nR - b;
      for (int off = 0; off < ncopy; off += blockDim.x) {
        int k2 = off + t; bool act = k2 < ncopy;
        int2 vr = make_int2(0, 0);
        if (act) vr = REC[srcBase + k2];
        __syncthreads();
        if (act) REC[destBase + k2] = vr;
        __syncthreads();
      }
    }
    __syncthreads();
    if (t < P) {
      int p = t; int kL = p << (j + 1), kR = kL + (1 << j);
      lcnt[kL] = lcnt[kL] - ca[p] + cM[p] + (lcnt[kR] - cb[p]);
    }
    __syncthreads();
  }
  if (t == 0) cnt[baseC] = lcnt[0];
}

// ---------- 5) ranks + transform, fully coalesced output ----------

__global__ void out_kernel(const u32* __restrict__ keyRaw, const u32* __restrict__ mm,
                           const u32* __restrict__ cdf,
                           const int2* __restrict__ REC,
                           const int* __restrict__ cnt, float* __restrict__ out) {
  int i = blockIdx.x * 256 + threadIdx.x;
  u32 key = keyRaw[i];
  u32 kmin = mm[0], kmax = mm[1];
  float smax = key_to_score(kmin);
  u32 g = bucket_of(key, kmin, kmax);
  int p = (int)cdf[g];               // block is bucket-aligned: position of bucket start
  int m = cnt[0];
  int lo = 0, hi = m - 1;
  while (lo < hi) {
    int mid = (lo + hi + 1) >> 1;
    if (REC[mid].x <= p) lo = mid; else hi = mid - 1;
  }
  int2 r = REC[lo];
  int s0 = r.x;
  int e0 = (lo + 1 < m) ? (REC[lo + 1].x - 1) : (N_ITEMS - 1);
  float SW = wsumf(s0, e0);
  float s = key_to_score(key);
  float rank = fexp(s - smax) * SW / recSY(r);
  out[i] = floorf(rank * (1.0f / 3.0f)) + 1.0f;
}

// ---------- launch ----------

extern "C" void kernel_launch(void* const* d_in, const int* in_sizes, int n_in,
                              void* d_out, int out_size, void* d_ws, size_t ws_size,
                              hipStream_t stream) {
  const float* x  = (const float*)d_in[0];
  const float* w1 = (const float*)d_in[1];
  const float* b1 = (const float*)d_in[2];
  const float* w2 = (const float*)d_in[3];
  const float* b2 = (const float*)d_in[4];
  float* out = (float*)d_out;

  char* ws = (char*)d_ws;
  size_t o = 0;
  u32* mm     = (u32*)(ws + o); o += 16;
  u32* pmin   = (u32*)(ws + o); o += (size_t)SCAN_BLOCKS * 4;
  u32* pmax   = (u32*)(ws + o); o += (size_t)SCAN_BLOCKS * 4;
  u64* hist8  = (u64*)(ws + o); o += (size_t)NSLICE * NB * 8;    // 4 MB, XCD-sliced
  u64* flags  = (u64*)(ws + o); o += (size_t)SCAN_BLOCKS * 8;
  u32* cdf    = (u32*)(ws + o); o += (size_t)(NB + 4) * 4;
  u32* cstart = (u32*)(ws + o); o += (size_t)(NCHUNKS + 4) * 4;
  u32* keyRaw = (u32*)(ws + o); o += (size_t)N_ITEMS * 4;
  int2* REC   = (int2*)(ws + o); o += (size_t)N_ITEMS * 8;
  int* cnt    = (int*)(ws + o);  o += (size_t)NCHUNKS * 4;

  score_key_kernel<<<SCAN_BLOCKS, 256, 0, stream>>>(x, w1, b1, w2, b2,
                                                    keyRaw, pmin, pmax, hist8, flags);
  hist_kernel<<<SCAN_BLOCKS, 256, 0, stream>>>(keyRaw, pmin, pmax, hist8, mm);
  scan_pav_kernel<<<SCAN_BLOCKS, 256, 0, stream>>>(hist8, flags, cdf, cstart, REC, cnt);
  // 11 tree levels in 3 launches: 0-4 (64 blocks), 5-7 (8 blocks), 8-10 (1 block x1024)
  merge_multi_kernel<<<64, 256, 0, stream>>>(REC, cnt, cstart, 0, 5);
  merge_multi_kernel<<<8, 256, 0, stream>>>(REC, cnt, cstart, 5, 3);
  merge_multi_kernel<<<1, 1024, 0, stream>>>(REC, cnt, cstart, 8, 3);
  out_kernel<<<SCAN_BLOCKS, 256, 0, stream>>>(keyRaw, mm, cdf, REC, cnt, out);
}

// Round 9
// 117.486 us; speedup vs baseline: 1.6472x; 1.1342x over previous
//
#include <hip/hip_runtime.h>
#include <stdint.h>

typedef unsigned int u32;
typedef unsigned long long u64;

#define N_ITEMS 131072
#define NB 131072                   // buckets (monotone in descending score)
#define NSLICE 4                    // XCD-sliced histogram copies
#define NCHUNKS 2048
#define MBLK 64                     // fused scan/pav/merge blocks
#define BUCK_PER_BLK 2048           // buckets per fused block
#define CH_PER_BLK 32               // chunks (64 buckets) per fused block
#define PAD 65                      // padded LDS record stride per chunk
#define REGSLOT 2048                // record slots per region in global REC
#define FIXSCALE 268435456.0f       // 2^28 fixed-point scale for sum(exp)
#define FIXMASK ((1ull << 46) - 1)

// ---------- helpers ----------

// sum_{i=s}^{e} (N - i) — exact weight-side sum of exp(w) over sorted positions
__device__ __forceinline__ float wsumf(int s, int e) {
  return 0.5f * (float)(e - s + 1) * (float)(2 * N_ITEMS - s - e);
}

__device__ __forceinline__ float key_to_score(u32 key) {
  u32 m = ~key;
  u32 u = (m & 0x80000000u) ? (m ^ 0x80000000u) : ~m;
  return __uint_as_float(u);
}

#define LOG2E 1.4426950408889634f
__device__ __forceinline__ float fexp(float x) { return exp2f(x * LOG2E); }

// ascending key == descending score; ascending bucket == descending score
__device__ __forceinline__ u32 bucket_of(u32 key, u32 kmin, u32 kmax) {
  double scale = (double)NB / ((double)(kmax - kmin) + 1.0);
  u32 b = (u32)((double)(key - kmin) * scale);
  return b < NB ? b : (NB - 1);
}

__device__ __forceinline__ float recSY(int2 r) { return __int_as_float(r.y); }

// ---------- 1) scores -> keys, per-block minmax partials, buffer zeroing ----------

__global__ void score_key_kernel(const float* __restrict__ x,
                                 const float* __restrict__ w1,
                                 const float* __restrict__ b1,
                                 const float* __restrict__ w2,
                                 const float* __restrict__ b2,
                                 u32* __restrict__ keyRaw,
                                 u32* __restrict__ pmin, u32* __restrict__ pmax,
                                 u64* __restrict__ hist8, u64* __restrict__ flags) {
  __shared__ u32 r0[256], r1[256];
  int t = threadIdx.x;
  int i = blockIdx.x * 256 + t;
#pragma unroll
  for (int k = 0; k < NSLICE; ++k) hist8[(size_t)k * NB + i] = 0ull;
  if (i < MBLK) flags[i] = 0ull;
  float xv = x[i];
  float s = b2[0];
#pragma unroll
  for (int j = 0; j < 32; ++j) {
    float h = fmaf(xv, w1[j], b1[j]);
    h = fmaxf(h, 0.0f);
    s = fmaf(h, w2[j], s);
  }
  u32 u = __float_as_uint(s);
  u32 m = u ^ ((u & 0x80000000u) ? 0xFFFFFFFFu : 0x80000000u); // ascending map
  u32 key = ~m;
  keyRaw[i] = key;
  r0[t] = key; r1[t] = key;
  __syncthreads();
  for (int off = 128; off > 0; off >>= 1) {
    if (t < off) { r0[t] = min(r0[t], r0[t + off]); r1[t] = max(r1[t], r1[t + off]); }
    __syncthreads();
  }
  if (t == 0) { pmin[blockIdx.x] = r0[0]; pmax[blockIdx.x] = r1[0]; }
}

// ---------- 2) bucket aggregates: ONE packed u64 atomic per item, XCD-sliced ----------
// bits [46:63] = count, bits [0:45] = fixed-point (2^28) sum of exp(s - smax)

__global__ void hist_kernel(const u32* __restrict__ keyRaw,
                            const u32* __restrict__ pmin, const u32* __restrict__ pmax,
                            u64* __restrict__ hist8, u32* __restrict__ mm) {
  __shared__ u32 s0[256], s1[256];
  int t = threadIdx.x;
  s0[t] = min(pmin[t], pmin[t + 256]);
  s1[t] = max(pmax[t], pmax[t + 256]);
  __syncthreads();
  for (int off = 128; off > 0; off >>= 1) {
    if (t < off) { s0[t] = min(s0[t], s0[t + off]); s1[t] = max(s1[t], s1[t + off]); }
    __syncthreads();
  }
  u32 kmin = s0[0], kmax = s1[0];
  if (blockIdx.x == 0 && t == 0) { mm[0] = kmin; mm[1] = kmax; }
  int i = blockIdx.x * 256 + t;
  u32 key = keyRaw[i];
  u32 g = bucket_of(key, kmin, kmax);
  float smax = key_to_score(kmin);
  float v = fexp(key_to_score(key) - smax);            // in (0, 1]
  u64 fix = (u64)fmaxf(1.0f, fmaf(v, FIXSCALE, 0.5f)); // clamp: SY can never be 0
  size_t slice = (size_t)(blockIdx.x & (NSLICE - 1)) * NB;
  atomicAdd(&hist8[slice + g], (1ull << 46) | fix);
}

// ---------- 3) fused: slice-reduce + lookback scan + PAV + merge levels 0-4 in LDS ----------
// One block owns 2048 buckets = 32 chunks = one whole level-0..4 merge region.

__global__ __launch_bounds__(256) void scan_pav_merge_kernel(
    const u64* __restrict__ hist8, u64* __restrict__ flags,
    u32* __restrict__ cdf, int2* __restrict__ REC,
    int* __restrict__ cnt2, u32* __restrict__ rstart) {
  __shared__ u32 vals[BUCK_PER_BLK + 1];   // counts -> global-exclusive cdf
  __shared__ float seL[BUCK_PER_BLK];
  __shared__ int   rST[CH_PER_BLK * PAD];
  __shared__ float rSY[CH_PER_BLK * PAD];
  __shared__ u32 sh[256];
  __shared__ u32 exclu_s;
  __shared__ int lcnt[CH_PER_BLK];
  __shared__ int ca[16], cb[16], cM[16];
  int t = threadIdx.x, b = blockIdx.x;
  int B0 = b * BUCK_PER_BLK;
  // coalesced load + slice reduce
  for (int q = 0; q < 8; ++q) {
    int ii = q * 256 + t;
    u64 acc = 0;
#pragma unroll
    for (int c = 0; c < NSLICE; ++c) acc += hist8[(size_t)c * NB + B0 + ii];
    vals[ii] = (u32)(acc >> 46);
    seL[ii] = (float)(acc & FIXMASK) * (1.0f / FIXSCALE);
  }
  __syncthreads();
  // per-thread local prefix over contiguous 8, then block scan
  u32 loc[8]; u32 s = 0;
  for (int q = 0; q < 8; ++q) { loc[q] = s; s += vals[t * 8 + q]; }
  sh[t] = s;
  __syncthreads();
  for (int off = 1; off < 256; off <<= 1) {
    u32 x2 = (t >= off) ? sh[t - off] : 0u;
    __syncthreads();
    sh[t] += x2;
    __syncthreads();
  }
  if (t == 0) {
    u32 agg = sh[255];
    if (b == 0) {
      atomicExch(&flags[0], (2ull << 32) | (u64)agg);
      exclu_s = 0u;
    } else {
      atomicExch(&flags[b], (1ull << 32) | (u64)agg);
      u32 ex = 0; int j = b - 1;
      for (;;) {
        u64 f = atomicAdd((u64*)&flags[j], 0ull);   // device-scope load
        u32 st = (u32)(f >> 32);
        if (st == 0u) continue;                     // spin: 64 blocks co-resident
        ex += (u32)f;
        if (st == 2u) break;
        --j;
      }
      atomicExch(&flags[b], (2ull << 32) | (u64)(ex + agg));
      exclu_s = ex;
    }
  }
  __syncthreads();
  u32 exclu = exclu_s;
  u32 tbase = ((t == 0) ? 0u : sh[t - 1]) + exclu;
  // overwrite vals with GLOBAL exclusive cdf; mirror to global (vectorized)
  u32 eb8[8];
  for (int q = 0; q < 8; ++q) { eb8[q] = tbase + loc[q]; vals[t * 8 + q] = eb8[q]; }
  {
    uint4* c4 = (uint4*)(cdf + B0 + t * 8);
    c4[0] = make_uint4(eb8[0], eb8[1], eb8[2], eb8[3]);
    c4[1] = make_uint4(eb8[4], eb8[5], eb8[6], eb8[7]);
  }
  if (t == 255) vals[BUCK_PER_BLK] = exclu + sh[255];
  if (t == 0) rstart[b] = exclu;
  if (b == 0 && t == 0) rstart[MBLK] = N_ITEMS;
  __syncthreads();
  // per-chunk PAV (32 threads), stack stored in place at padded stride
  if (t < CH_PER_BLK) {
    int base = t * PAD;
    int ptr = 0; bool have = false;
    float syT = 0.0f; int stT = 0;
    for (int k = 0; k < 64; ++k) {
      u32 cs = vals[t * 64 + k], ce = vals[t * 64 + k + 1];
      if (ce == cs) continue;                 // empty bucket
      float syC = seL[t * 64 + k];
      int stC = (int)cs, eC = (int)ce - 1;
      while (have) {
        float SWc = wsumf(stC, eC);
        float SWt = wsumf(stT, stC - 1);
        if (!(syT * SWc <= syC * SWt)) break; // merge while val_top <= val_cur
        syC += syT; stC = stT;
        if (ptr == 0) { have = false; break; }
        --ptr;
        stT = rST[base + ptr]; syT = rSY[base + ptr];
      }
      if (have) { rST[base + ptr] = stT; rSY[base + ptr] = syT; ++ptr; }
      stT = stC; syT = syC; have = true;
    }
    if (have) { rST[base + ptr] = stT; rSY[base + ptr] = syT; ++ptr; }
    lcnt[t] = ptr;
  }
  __syncthreads();
  // merge levels 0..4 entirely in LDS
  for (int j = 0; j < 5; ++j) {
    int P = CH_PER_BLK >> (j + 1);
    if (t < P) {
      int p = t;
      int kL = p << (j + 1), kR = kL + (1 << j);
      int slotL = kL * PAD, slotR = kR * PAD;
      int nL = lcnt[kL], nR = lcnt[kR];
      int a = 0, bb = 0, hasM = 0;
      if (nL > 0 && nR > 0) {
        int gstartR = (int)vals[kR * 64];
        int gendR   = (int)vals[(kR + (1 << j)) * 64];
        float SYL = rSY[slotL + nL - 1]; int stL = rST[slotL + nL - 1];
        float SYR = rSY[slotR];
        int eR = (nR > 1) ? (rST[slotR + 1] - 1) : (gendR - 1);
        float SWL = wsumf(stL, gstartR - 1);
        float SWR = wsumf(gstartR, eR);
        if (SYL * SWR <= SYR * SWL) {
          hasM = 1;
          float SYM = SYL + SYR; int Ms = stL, Me = eR;
          a = 1; bb = 1;
          for (;;) {
            float SWM = wsumf(Ms, Me);
            if (a < nL) {
              float SYe = rSY[slotL + nL - 1 - a]; int ste = rST[slotL + nL - 1 - a];
              float SWe = wsumf(ste, Ms - 1);
              if (SYe * SWM <= SYM * SWe) { SYM += SYe; Ms = ste; ++a; continue; }
            }
            if (bb < nR) {
              float SYb = rSY[slotR + bb]; int sb = rST[slotR + bb];
              int eb = (bb + 1 < nR) ? (rST[slotR + bb + 1] - 1) : (gendR - 1);
              float SWb = wsumf(sb, eb);
              if (SYM * SWb <= SYb * SWM) { SYM += SYb; Me = eb; ++bb; continue; }
            }
            break;
          }
          rST[slotL + nL - a] = Ms; rSY[slotL + nL - a] = SYM;
        }
      }
      ca[p] = a; cb[p] = bb; cM[p] = hasM;
    }
    __syncthreads();
    for (int p = 0; p < P; ++p) {
      int kL = p << (j + 1), kR = kL + (1 << j);
      int nL = lcnt[kL], nR = lcnt[kR];
      int a = ca[p], bb = cb[p], hasM = cM[p];
      int slotL = kL * PAD, slotR = kR * PAD;
      int destBase = slotL + nL - a + hasM;
      int srcBase = slotR + bb;
      int ncopy = nR - bb;
      for (int off = 0; off < ncopy; off += blockDim.x) {
        int k2 = off + t; bool act = k2 < ncopy;
        int vt = 0; float vs = 0.f;
        if (act) { vt = rST[srcBase + k2]; vs = rSY[srcBase + k2]; }
        __syncthreads();
        if (act) { rST[destBase + k2] = vt; rSY[destBase + k2] = vs; }
        __syncthreads();
      }
    }
    __syncthreads();
    if (t < P) {
      int p = t; int kL = p << (j + 1), kR = kL + (1 << j);
      lcnt[kL] = lcnt[kL] - ca[p] + cM[p] + (lcnt[kR] - cb[p]);
    }
    __syncthreads();
  }
  // write region records (coalesced) + count
  int n = lcnt[0];
  for (int k = t; k < n; k += blockDim.x)
    REC[(size_t)b * REGSLOT + k] = make_int2(rST[k], __float_as_int(rSY[k]));
  if (t == 0) cnt2[b] = n;
}

// ---------- 4) region-granularity tree merge (levels 5-10, 2 launches) ----------

__global__ void merge_region_kernel(int2* __restrict__ REC, int* __restrict__ cnt2,
                                    const u32* __restrict__ rstart, int l0, int L) {
  __shared__ int lcnt[8];
  __shared__ int ca[4], cb[4], cM[4];
  int t = threadIdx.x;
  int G = 1 << L;                  // incoming groups per block
  int SR = 1 << l0;                // regions per incoming group
  int baseR = blockIdx.x * G * SR;
  if (t < G) lcnt[t] = cnt2[baseR + t * SR];
  __syncthreads();
  for (int j = 0; j < L; ++j) {
    int P = G >> (j + 1);
    if (t < P) {
      int p = t;
      int kL = p << (j + 1), kR = kL + (1 << j);
      int slotL = (baseR + kL * SR) * REGSLOT, slotR = (baseR + kR * SR) * REGSLOT;
      int nL = lcnt[kL], nR = lcnt[kR];
      int a = 0, bb = 0, hasM = 0;
      if (nL > 0 && nR > 0) {
        int gstartR = (int)rstart[baseR + kR * SR];
        int gendR   = (int)rstart[baseR + (kR + (1 << j)) * SR];
        int2 rL = REC[slotL + nL - 1];
        float SYL = recSY(rL); int stL = rL.x;
        int2 rR = REC[slotR];
        float SYR = recSY(rR);
        int eR = (nR > 1) ? (REC[slotR + 1].x - 1) : (gendR - 1);
        float SWL = wsumf(stL, gstartR - 1);
        float SWR = wsumf(gstartR, eR);
        if (SYL * SWR <= SYR * SWL) {
          hasM = 1;
          float SYM = SYL + SYR; int Ms = stL, Me = eR;
          a = 1; bb = 1;
          for (;;) {
            float SWM = wsumf(Ms, Me);
            if (a < nL) {
              int2 re = REC[slotL + nL - 1 - a];
              float SYe = recSY(re); int ste = re.x;
              float SWe = wsumf(ste, Ms - 1);
              if (SYe * SWM <= SYM * SWe) { SYM += SYe; Ms = ste; ++a; continue; }
            }
            if (bb < nR) {
              int2 rb = REC[slotR + bb];
              float SYb = recSY(rb); int sb = rb.x;
              int eb = (bb + 1 < nR) ? (REC[slotR + bb + 1].x - 1) : (gendR - 1);
              float SWb = wsumf(sb, eb);
              if (SYM * SWb <= SYb * SWM) { SYM += SYb; Me = eb; ++bb; continue; }
            }
            break;
          }
          REC[slotL + nL - a] = make_int2(Ms, __float_as_int(SYM));
        }
      }
      ca[p] = a; cb[p] = bb; cM[p] = hasM;
    }
    __syncthreads();
    // staged compaction copies (dest <= src)
    for (int p = 0; p < P; ++p) {
      int kL = p << (j + 1), kR = kL + (1 << j);
      int nL = lcnt[kL], nR = lcnt[kR];
      int a = ca[p], bb = cb[p], hasM = cM[p];
      int slotL = (baseR + kL * SR) * REGSLOT, slotR = (baseR + kR * SR) * REGSLOT;
      int destBase = slotL + nL - a + hasM;
      int srcBase = slotR + bb;
      int ncopy = nR - bb;
      for (int off = 0; off < ncopy; off += blockDim.x) {
        int k2 = off + t; bool act = k2 < ncopy;
        int2 vr = make_int2(0, 0);
        if (act) vr = REC[srcBase + k2];
        __syncthreads();
        if (act) REC[destBase + k2] = vr;
        __syncthreads();
      }
    }
    __syncthreads();
    if (t < P) {
      int p = t; int kL = p << (j + 1), kR = kL + (1 << j);
      lcnt[kL] = lcnt[kL] - ca[p] + cM[p] + (lcnt[kR] - cb[p]);
    }
    __syncthreads();
  }
  if (t == 0) cnt2[baseR] = lcnt[0];
}

// ---------- 5) ranks + transform, fully coalesced output ----------

__global__ void out_kernel(const u32* __restrict__ keyRaw, const u32* __restrict__ mm,
                           const u32* __restrict__ cdf,
                           const int2* __restrict__ REC,
                           const int* __restrict__ cnt2, float* __restrict__ out) {
  int i = blockIdx.x * 256 + threadIdx.x;
  u32 key = keyRaw[i];
  u32 kmin = mm[0], kmax = mm[1];
  float smax = key_to_score(kmin);
  u32 g = bucket_of(key, kmin, kmax);
  int p = (int)cdf[g];               // block is bucket-aligned: position of bucket start
  int m = cnt2[0];
  int lo = 0, hi = m - 1;
  while (lo < hi) {
    int mid = (lo + hi + 1) >> 1;
    if (REC[mid].x <= p) lo = mid; else hi = mid - 1;
  }
  int2 r = REC[lo];
  int s0 = r.x;
  int e0 = (lo + 1 < m) ? (REC[lo + 1].x - 1) : (N_ITEMS - 1);
  float SW = wsumf(s0, e0);
  float s = key_to_score(key);
  float rank = fexp(s - smax) * SW / recSY(r);
  out[i] = floorf(rank * (1.0f / 3.0f)) + 1.0f;
}

// ---------- launch ----------

extern "C" void kernel_launch(void* const* d_in, const int* in_sizes, int n_in,
                              void* d_out, int out_size, void* d_ws, size_t ws_size,
                              hipStream_t stream) {
  const float* x  = (const float*)d_in[0];
  const float* w1 = (const float*)d_in[1];
  const float* b1 = (const float*)d_in[2];
  const float* w2 = (const float*)d_in[3];
  const float* b2 = (const float*)d_in[4];
  float* out = (float*)d_out;

  char* ws = (char*)d_ws;
  size_t o = 0;
  u32* mm     = (u32*)(ws + o); o += 16;
  u32* pmin   = (u32*)(ws + o); o += (size_t)512 * 4;
  u32* pmax   = (u32*)(ws + o); o += (size_t)512 * 4;
  u64* hist8  = (u64*)(ws + o); o += (size_t)NSLICE * NB * 8;    // 4 MB, XCD-sliced
  u64* flags  = (u64*)(ws + o); o += (size_t)MBLK * 8;
  u32* cdf    = (u32*)(ws + o); o += (size_t)(NB + 4) * 4;
  u32* rstart = (u32*)(ws + o); o += (size_t)(MBLK + 4) * 4;
  u32* keyRaw = (u32*)(ws + o); o += (size_t)N_ITEMS * 4;
  int2* REC   = (int2*)(ws + o); o += (size_t)N_ITEMS * 8;
  int* cnt2   = (int*)(ws + o);  o += (size_t)MBLK * 4;

  score_key_kernel<<<512, 256, 0, stream>>>(x, w1, b1, w2, b2,
                                            keyRaw, pmin, pmax, hist8, flags);
  hist_kernel<<<512, 256, 0, stream>>>(keyRaw, pmin, pmax, hist8, mm);
  scan_pav_merge_kernel<<<MBLK, 256, 0, stream>>>(hist8, flags, cdf, REC, cnt2, rstart);
  // levels 5-7 (8 blocks of 8 regions), levels 8-10 (1 block x 1024, groups of 8)
  merge_region_kernel<<<8, 256, 0, stream>>>(REC, cnt2, rstart, 0, 3);
  merge_region_kernel<<<1, 1024, 0, stream>>>(REC, cnt2, rstart, 3, 3);
  out_kernel<<<512, 256, 0, stream>>>(keyRaw, mm, cdf, REC, cnt2, out);
}

// Round 10
// 114.646 us; speedup vs baseline: 1.6880x; 1.0248x over previous
//
#include <hip/hip_runtime.h>
#include <stdint.h>

typedef unsigned int u32;
typedef unsigned long long u64;

#define N_ITEMS 131072
#define NB 131072                   // buckets (monotone in descending score)
#define NSLICE 4                    // XCD-sliced histogram copies
#define NCHUNKS 2048
#define MBLK 64                     // fused scan/pav/merge blocks
#define BUCK_PER_BLK 2048           // buckets per fused block
#define CH_PER_BLK 32               // chunks (64 buckets) per fused block
#define PAD 65                      // padded LDS record stride per chunk
#define REGSLOT 2048                // record slots per region in global REC
#define FIXSCALE 268435456.0f       // 2^28 fixed-point scale for sum(exp)
#define FIXMASK ((1ull << 46) - 1)

// ---------- helpers ----------

// sum_{i=s}^{e} (N - i) — exact weight-side sum of exp(w) over sorted positions
__device__ __forceinline__ float wsumf(int s, int e) {
  return 0.5f * (float)(e - s + 1) * (float)(2 * N_ITEMS - s - e);
}

__device__ __forceinline__ float key_to_score(u32 key) {
  u32 m = ~key;
  u32 u = (m & 0x80000000u) ? (m ^ 0x80000000u) : ~m;
  return __uint_as_float(u);
}

#define LOG2E 1.4426950408889634f
__device__ __forceinline__ float fexp(float x) { return exp2f(x * LOG2E); }

// ascending key == descending score; ascending bucket == descending score
__device__ __forceinline__ u32 bucket_of(u32 key, u32 kmin, u32 kmax) {
  double scale = (double)NB / ((double)(kmax - kmin) + 1.0);
  u32 b = (u32)((double)(key - kmin) * scale);
  return b < NB ? b : (NB - 1);
}

__device__ __forceinline__ float recSY(int2 r) { return __int_as_float(r.y); }

// ---------- 1) scores -> keys, per-block minmax partials, buffer zeroing ----------

__global__ void score_key_kernel(const float* __restrict__ x,
                                 const float* __restrict__ w1,
                                 const float* __restrict__ b1,
                                 const float* __restrict__ w2,
                                 const float* __restrict__ b2,
                                 u32* __restrict__ keyRaw,
                                 u32* __restrict__ pmin, u32* __restrict__ pmax,
                                 u64* __restrict__ hist8, u64* __restrict__ flags) {
  __shared__ u32 r0[256], r1[256];
  int t = threadIdx.x;
  int i = blockIdx.x * 256 + t;
#pragma unroll
  for (int k = 0; k < NSLICE; ++k) hist8[(size_t)k * NB + i] = 0ull;
  if (i < MBLK) flags[i] = 0ull;
  float xv = x[i];
  float s = b2[0];
#pragma unroll
  for (int j = 0; j < 32; ++j) {
    float h = fmaf(xv, w1[j], b1[j]);
    h = fmaxf(h, 0.0f);
    s = fmaf(h, w2[j], s);
  }
  u32 u = __float_as_uint(s);
  u32 m = u ^ ((u & 0x80000000u) ? 0xFFFFFFFFu : 0x80000000u); // ascending map
  u32 key = ~m;
  keyRaw[i] = key;
  r0[t] = key; r1[t] = key;
  __syncthreads();
  for (int off = 128; off > 0; off >>= 1) {
    if (t < off) { r0[t] = min(r0[t], r0[t + off]); r1[t] = max(r1[t], r1[t + off]); }
    __syncthreads();
  }
  if (t == 0) { pmin[blockIdx.x] = r0[0]; pmax[blockIdx.x] = r1[0]; }
}

// ---------- 2) bucket aggregates: ONE packed u64 atomic per item, XCD-sliced ----------
// bits [46:63] = count, bits [0:45] = fixed-point (2^28) sum of exp(s - smax)

__global__ void hist_kernel(const u32* __restrict__ keyRaw,
                            const u32* __restrict__ pmin, const u32* __restrict__ pmax,
                            u64* __restrict__ hist8, u32* __restrict__ mm) {
  __shared__ u32 s0[256], s1[256];
  int t = threadIdx.x;
  s0[t] = min(pmin[t], pmin[t + 256]);
  s1[t] = max(pmax[t], pmax[t + 256]);
  __syncthreads();
  for (int off = 128; off > 0; off >>= 1) {
    if (t < off) { s0[t] = min(s0[t], s0[t + off]); s1[t] = max(s1[t], s1[t + off]); }
    __syncthreads();
  }
  u32 kmin = s0[0], kmax = s1[0];
  if (blockIdx.x == 0 && t == 0) { mm[0] = kmin; mm[1] = kmax; }
  int i = blockIdx.x * 256 + t;
  u32 key = keyRaw[i];
  u32 g = bucket_of(key, kmin, kmax);
  float smax = key_to_score(kmin);
  float v = fexp(key_to_score(key) - smax);            // in (0, 1]
  u64 fix = (u64)fmaxf(1.0f, fmaf(v, FIXSCALE, 0.5f)); // clamp: SY can never be 0
  size_t slice = (size_t)(blockIdx.x & (NSLICE - 1)) * NB;
  atomicAdd(&hist8[slice + g], (1ull << 46) | fix);
}

// ---------- 3) fused: slice-reduce + parallel wait-all scan + PAV + merge 0-4 in LDS ----------
// One block owns 2048 buckets = 32 chunks = one whole level-0..4 merge region.

__global__ __launch_bounds__(256) void scan_pav_merge_kernel(
    const u64* __restrict__ hist8, u64* __restrict__ flags,
    u32* __restrict__ cdf, int2* __restrict__ REC,
    int* __restrict__ cnt2, u32* __restrict__ rstart) {
  __shared__ u32 vals[BUCK_PER_BLK + 1];   // counts -> global-exclusive cdf
  __shared__ float seL[BUCK_PER_BLK];
  __shared__ int   rST[CH_PER_BLK * PAD];
  __shared__ float rSY[CH_PER_BLK * PAD];
  __shared__ u32 sh[256];
  __shared__ u32 red64[64];
  __shared__ int lcnt[CH_PER_BLK];
  __shared__ int ca[16], cb[16], cM[16];
  int t = threadIdx.x, b = blockIdx.x;
  int B0 = b * BUCK_PER_BLK;
  // coalesced load + slice reduce
  for (int q = 0; q < 8; ++q) {
    int ii = q * 256 + t;
    u64 acc = 0;
#pragma unroll
    for (int c = 0; c < NSLICE; ++c) acc += hist8[(size_t)c * NB + B0 + ii];
    vals[ii] = (u32)(acc >> 46);
    seL[ii] = (float)(acc & FIXMASK) * (1.0f / FIXSCALE);
  }
  __syncthreads();
  // per-thread local prefix over contiguous 8, then block scan
  u32 loc[8]; u32 s = 0;
  for (int q = 0; q < 8; ++q) { loc[q] = s; s += vals[t * 8 + q]; }
  sh[t] = s;
  __syncthreads();
  for (int off = 1; off < 256; off <<= 1) {
    u32 x2 = (t >= off) ? sh[t - off] : 0u;
    __syncthreads();
    sh[t] += x2;
    __syncthreads();
  }
  // publish aggregate immediately; then PARALLEL wait-all over predecessors:
  // lane t spins on flags[t] (independent atomics, one wave) — no serial chain.
  if (t == 0) atomicExch(&flags[b], (1ull << 32) | (u64)sh[255]);
  if (t < 64) {
    u32 v = 0;
    if (t < b) {
      u64 f;
      do { f = atomicAdd(&flags[t], 0ull); } while ((u32)(f >> 32) == 0u);
      v = (u32)f;
    }
    red64[t] = v;
  }
  __syncthreads();
  for (int off = 32; off > 0; off >>= 1) {
    if (t < off) red64[t] += red64[t + off];
    __syncthreads();
  }
  u32 exclu = red64[0];
  u32 tbase = ((t == 0) ? 0u : sh[t - 1]) + exclu;
  // overwrite vals with GLOBAL exclusive cdf; mirror to global (vectorized)
  u32 eb8[8];
  for (int q = 0; q < 8; ++q) { eb8[q] = tbase + loc[q]; vals[t * 8 + q] = eb8[q]; }
  {
    uint4* c4 = (uint4*)(cdf + B0 + t * 8);
    c4[0] = make_uint4(eb8[0], eb8[1], eb8[2], eb8[3]);
    c4[1] = make_uint4(eb8[4], eb8[5], eb8[6], eb8[7]);
  }
  if (t == 255) vals[BUCK_PER_BLK] = exclu + sh[255];
  if (t == 0) rstart[b] = exclu;
  if (b == 0 && t == 0) rstart[MBLK] = N_ITEMS;
  __syncthreads();
  // per-chunk PAV (32 threads), stack stored in place at padded stride
  if (t < CH_PER_BLK) {
    int base = t * PAD;
    int ptr = 0; bool have = false;
    float syT = 0.0f; int stT = 0;
    for (int k = 0; k < 64; ++k) {
      u32 cs = vals[t * 64 + k], ce = vals[t * 64 + k + 1];
      if (ce == cs) continue;                 // empty bucket
      float syC = seL[t * 64 + k];
      int stC = (int)cs, eC = (int)ce - 1;
      while (have) {
        float SWc = wsumf(stC, eC);
        float SWt = wsumf(stT, stC - 1);
        if (!(syT * SWc <= syC * SWt)) break; // merge while val_top <= val_cur
        syC += syT; stC = stT;
        if (ptr == 0) { have = false; break; }
        --ptr;
        stT = rST[base + ptr]; syT = rSY[base + ptr];
      }
      if (have) { rST[base + ptr] = stT; rSY[base + ptr] = syT; ++ptr; }
      stT = stC; syT = syC; have = true;
    }
    if (have) { rST[base + ptr] = stT; rSY[base + ptr] = syT; ++ptr; }
    lcnt[t] = ptr;
  }
  __syncthreads();
  // merge levels 0..4 entirely in LDS
  for (int j = 0; j < 5; ++j) {
    int P = CH_PER_BLK >> (j + 1);
    if (t < P) {
      int p = t;
      int kL = p << (j + 1), kR = kL + (1 << j);
      int slotL = kL * PAD, slotR = kR * PAD;
      int nL = lcnt[kL], nR = lcnt[kR];
      int a = 0, bb = 0, hasM = 0;
      if (nL > 0 && nR > 0) {
        int gstartR = (int)vals[kR * 64];
        int gendR   = (int)vals[(kR + (1 << j)) * 64];
        float SYL = rSY[slotL + nL - 1]; int stL = rST[slotL + nL - 1];
        float SYR = rSY[slotR];
        int eR = (nR > 1) ? (rST[slotR + 1] - 1) : (gendR - 1);
        float SWL = wsumf(stL, gstartR - 1);
        float SWR = wsumf(gstartR, eR);
        if (SYL * SWR <= SYR * SWL) {
          hasM = 1;
          float SYM = SYL + SYR; int Ms = stL, Me = eR;
          a = 1; bb = 1;
          for (;;) {
            float SWM = wsumf(Ms, Me);
            if (a < nL) {
              float SYe = rSY[slotL + nL - 1 - a]; int ste = rST[slotL + nL - 1 - a];
              float SWe = wsumf(ste, Ms - 1);
              if (SYe * SWM <= SYM * SWe) { SYM += SYe; Ms = ste; ++a; continue; }
            }
            if (bb < nR) {
              float SYb = rSY[slotR + bb]; int sb = rST[slotR + bb];
              int eb = (bb + 1 < nR) ? (rST[slotR + bb + 1] - 1) : (gendR - 1);
              float SWb = wsumf(sb, eb);
              if (SYM * SWb <= SYb * SWM) { SYM += SYb; Me = eb; ++bb; continue; }
            }
            break;
          }
          rST[slotL + nL - a] = Ms; rSY[slotL + nL - a] = SYM;
        }
      }
      ca[p] = a; cb[p] = bb; cM[p] = hasM;
    }
    __syncthreads();
    for (int p = 0; p < P; ++p) {
      int kL = p << (j + 1), kR = kL + (1 << j);
      int nL = lcnt[kL], nR = lcnt[kR];
      int a = ca[p], bb = cb[p], hasM = cM[p];
      int slotL = kL * PAD, slotR = kR * PAD;
      int destBase = slotL + nL - a + hasM;
      int srcBase = slotR + bb;
      int ncopy = nR - bb;
      for (int off = 0; off < ncopy; off += blockDim.x) {
        int k2 = off + t; bool act = k2 < ncopy;
        int vt = 0; float vs = 0.f;
        if (act) { vt = rST[srcBase + k2]; vs = rSY[srcBase + k2]; }
        __syncthreads();
        if (act) { rST[destBase + k2] = vt; rSY[destBase + k2] = vs; }
        __syncthreads();
      }
    }
    __syncthreads();
    if (t < P) {
      int p = t; int kL = p << (j + 1), kR = kL + (1 << j);
      lcnt[kL] = lcnt[kL] - ca[p] + cM[p] + (lcnt[kR] - cb[p]);
    }
    __syncthreads();
  }
  // write region records (coalesced) + count
  int n = lcnt[0];
  for (int k = t; k < n; k += blockDim.x)
    REC[(size_t)b * REGSLOT + k] = make_int2(rST[k], __float_as_int(rSY[k]));
  if (t == 0) cnt2[b] = n;
}

// ---------- 4) region-granularity tree merge (levels 5-10, 2 launches) ----------

__global__ void merge_region_kernel(int2* __restrict__ REC, int* __restrict__ cnt2,
                                    const u32* __restrict__ rstart, int l0, int L) {
  __shared__ int lcnt[8];
  __shared__ int ca[4], cb[4], cM[4];
  int t = threadIdx.x;
  int G = 1 << L;                  // incoming groups per block
  int SR = 1 << l0;                // regions per incoming group
  int baseR = blockIdx.x * G * SR;
  if (t < G) lcnt[t] = cnt2[baseR + t * SR];
  __syncthreads();
  for (int j = 0; j < L; ++j) {
    int P = G >> (j + 1);
    if (t < P) {
      int p = t;
      int kL = p << (j + 1), kR = kL + (1 << j);
      int slotL = (baseR + kL * SR) * REGSLOT, slotR = (baseR + kR * SR) * REGSLOT;
      int nL = lcnt[kL], nR = lcnt[kR];
      int a = 0, bb = 0, hasM = 0;
      if (nL > 0 && nR > 0) {
        int gstartR = (int)rstart[baseR + kR * SR];
        int gendR   = (int)rstart[baseR + (kR + (1 << j)) * SR];
        int2 rL = REC[slotL + nL - 1];
        float SYL = recSY(rL); int stL = rL.x;
        int2 rR = REC[slotR];
        float SYR = recSY(rR);
        int eR = (nR > 1) ? (REC[slotR + 1].x - 1) : (gendR - 1);
        float SWL = wsumf(stL, gstartR - 1);
        float SWR = wsumf(gstartR, eR);
        if (SYL * SWR <= SYR * SWL) {
          hasM = 1;
          float SYM = SYL + SYR; int Ms = stL, Me = eR;
          a = 1; bb = 1;
          for (;;) {
            float SWM = wsumf(Ms, Me);
            if (a < nL) {
              int2 re = REC[slotL + nL - 1 - a];
              float SYe = recSY(re); int ste = re.x;
              float SWe = wsumf(ste, Ms - 1);
              if (SYe * SWM <= SYM * SWe) { SYM += SYe; Ms = ste; ++a; continue; }
            }
            if (bb < nR) {
              int2 rb = REC[slotR + bb];
              float SYb = recSY(rb); int sb = rb.x;
              int eb = (bb + 1 < nR) ? (REC[slotR + bb + 1].x - 1) : (gendR - 1);
              float SWb = wsumf(sb, eb);
              if (SYM * SWb <= SYb * SWM) { SYM += SYb; Me = eb; ++bb; continue; }
            }
            break;
          }
          REC[slotL + nL - a] = make_int2(Ms, __float_as_int(SYM));
        }
      }
      ca[p] = a; cb[p] = bb; cM[p] = hasM;
    }
    __syncthreads();
    // staged compaction copies (dest <= src)
    for (int p = 0; p < P; ++p) {
      int kL = p << (j + 1), kR = kL + (1 << j);
      int nL = lcnt[kL], nR = lcnt[kR];
      int a = ca[p], bb = cb[p], hasM = cM[p];
      int slotL = (baseR + kL * SR) * REGSLOT, slotR = (baseR + kR * SR) * REGSLOT;
      int destBase = slotL + nL - a + hasM;
      int srcBase = slotR + bb;
      int ncopy = nR - bb;
      for (int off = 0; off < ncopy; off += blockDim.x) {
        int k2 = off + t; bool act = k2 < ncopy;
        int2 vr = make_int2(0, 0);
        if (act) vr = REC[srcBase + k2];
        __syncthreads();
        if (act) REC[destBase + k2] = vr;
        __syncthreads();
      }
    }
    __syncthreads();
    if (t < P) {
      int p = t; int kL = p << (j + 1), kR = kL + (1 << j);
      lcnt[kL] = lcnt[kL] - ca[p] + cM[p] + (lcnt[kR] - cb[p]);
    }
    __syncthreads();
  }
  if (t == 0) cnt2[baseR] = lcnt[0];
}

// ---------- 5) ranks + transform, fully coalesced output ----------

__global__ void out_kernel(const u32* __restrict__ keyRaw, const u32* __restrict__ mm,
                           const u32* __restrict__ cdf,
                           const int2* __restrict__ REC,
                           const int* __restrict__ cnt2, float* __restrict__ out) {
  int i = blockIdx.x * 256 + threadIdx.x;
  u32 key = keyRaw[i];
  u32 kmin = mm[0], kmax = mm[1];
  float smax = key_to_score(kmin);
  u32 g = bucket_of(key, kmin, kmax);
  int p = (int)cdf[g];               // block is bucket-aligned: position of bucket start
  int m = cnt2[0];
  int lo = 0, hi = m - 1;
  while (lo < hi) {
    int mid = (lo + hi + 1) >> 1;
    if (REC[mid].x <= p) lo = mid; else hi = mid - 1;
  }
  int2 r = REC[lo];
  int s0 = r.x;
  int e0 = (lo + 1 < m) ? (REC[lo + 1].x - 1) : (N_ITEMS - 1);
  float SW = wsumf(s0, e0);
  float s = key_to_score(key);
  float rank = fexp(s - smax) * SW / recSY(r);
  out[i] = floorf(rank * (1.0f / 3.0f)) + 1.0f;
}

// ---------- launch ----------

extern "C" void kernel_launch(void* const* d_in, const int* in_sizes, int n_in,
                              void* d_out, int out_size, void* d_ws, size_t ws_size,
                              hipStream_t stream) {
  const float* x  = (const float*)d_in[0];
  const float* w1 = (const float*)d_in[1];
  const float* b1 = (const float*)d_in[2];
  const float* w2 = (const float*)d_in[3];
  const float* b2 = (const float*)d_in[4];
  float* out = (float*)d_out;

  char* ws = (char*)d_ws;
  size_t o = 0;
  u32* mm     = (u32*)(ws + o); o += 16;
  u32* pmin   = (u32*)(ws + o); o += (size_t)512 * 4;
  u32* pmax   = (u32*)(ws + o); o += (size_t)512 * 4;
  u64* hist8  = (u64*)(ws + o); o += (size_t)NSLICE * NB * 8;    // 4 MB, XCD-sliced
  u64* flags  = (u64*)(ws + o); o += (size_t)MBLK * 8;
  u32* cdf    = (u32*)(ws + o); o += (size_t)(NB + 4) * 4;
  u32* rstart = (u32*)(ws + o); o += (size_t)(MBLK + 4) * 4;
  u32* keyRaw = (u32*)(ws + o); o += (size_t)N_ITEMS * 4;
  int2* REC   = (int2*)(ws + o); o += (size_t)N_ITEMS * 8;
  int* cnt2   = (int*)(ws + o);  o += (size_t)MBLK * 4;

  score_key_kernel<<<512, 256, 0, stream>>>(x, w1, b1, w2, b2,
                                            keyRaw, pmin, pmax, hist8, flags);
  hist_kernel<<<512, 256, 0, stream>>>(keyRaw, pmin, pmax, hist8, mm);
  scan_pav_merge_kernel<<<MBLK, 256, 0, stream>>>(hist8, flags, cdf, REC, cnt2, rstart);
  // levels 5-7 (8 blocks of 8 regions), levels 8-10 (1 block x 1024, groups of 8)
  merge_region_kernel<<<8, 256, 0, stream>>>(REC, cnt2, rstart, 0, 3);
  merge_region_kernel<<<1, 1024, 0, stream>>>(REC, cnt2, rstart, 3, 3);
  out_kernel<<<512, 256, 0, stream>>>(keyRaw, mm, cdf, REC, cnt2, out);
}